// Round 3
// baseline (904.229 us; speedup 1.0000x reference)
//
#include <hip/hip_runtime.h>
#include <math.h>

#define N    4096
#define NO   4097   // output spatial dim
#define TI   32     // output tile rows
#define TJ   16     // output tile cols
// hist region: rows TI+3=35 (i0-2..i0+32), cols TJ+3=19 (j0-2..j0+16)
// x halo:      rows TI+5=37 (i0-3..i0+33), cols TJ+5=21 (j0-3..j0+17)

struct OrientCoef { float c[8]; float s[8]; };

// LDS = xs 3256B + hsum 19040B = 22.3 KB -> 7 blocks/CU = 28 waves/CU (87%)
__global__ __launch_bounds__(256) void sift_fused(const float* __restrict__ x,
                                                  float* __restrict__ out,
                                                  OrientCoef cf) {
    const int i0  = blockIdx.y * TI;
    const int j0  = blockIdx.x * TJ;
    const int tid = threadIdx.x;

    __shared__ float xs[37][22];
    alignas(16) __shared__ float hsum[8][35][17];   // 8*35*17 = 4760 floats

    // ---- stage x halo (zero-padded) + zero hsum (float4) ----
    for (int l = tid; l < 37 * 21; l += 256) {
        int lr = l / 21, lc = l % 21;
        int gr = i0 - 3 + lr, gc = j0 - 3 + lc;
        float v = 0.0f;
        if (gr >= 0 && gr < N && gc >= 0 && gc < N) v = x[(size_t)gr * N + gc];
        xs[lr][lc] = v;
    }
    float4* hz = (float4*)&hsum[0][0][0];
    for (int l = tid; l < (8 * 35 * 17) / 4; l += 256) hz[l] = make_float4(0.f, 0.f, 0.f, 0.f);
    __syncthreads();

    // ---- Sobel + orientation argmax + fused horizontal scatter (LDS atomics) ----
    float* hflat = &hsum[0][0][0];
    for (int l = tid; l < 35 * 19; l += 256) {
        int lr = l / 19, lc = l % 19;
        int gr = i0 - 2 + lr, gc = j0 - 2 + lc;
        if (gr >= 0 && gr < N && gc >= 0 && gc < N) {
            float x00 = xs[lr][lc],     x01 = xs[lr][lc + 1],     x02 = xs[lr][lc + 2];
            float x10 = xs[lr + 1][lc],                           x12 = xs[lr + 1][lc + 2];
            float x20 = xs[lr + 2][lc], x21 = xs[lr + 2][lc + 1], x22 = xs[lr + 2][lc + 2];
            // unflipped sobel taps (lax conv = cross-correlation)
            float dx = (x02 - x00) + 2.0f * (x12 - x10) + (x22 - x20);
            float dy = (x20 - x00) + 2.0f * (x21 - x01) + (x22 - x02);
            float mag = sqrtf(dx * dx + dy * dy);
            int best = 0;
            float bv = fmaf(cf.s[0], dy, cf.c[0] * dx);
            #pragma unroll
            for (int o = 1; o < 8; ++o) {
                float cs = fmaf(cf.s[o], dy, cf.c[o] * dx);
                if (cs > bv) { bv = cs; best = o; }
            }
            float* rowp = hflat + (best * 35 + lr) * 17;
            #pragma unroll
            for (int w = 0; w < 4; ++w) {
                int jt = lc - 3 + w;
                if (jt >= 0 && jt < TJ) atomicAdd(rowp + jt, mag);  // ds_add_f32
            }
        }
    }
    __syncthreads();

    // ---- vertical 4-row sum + store: 8 ch * 32 i * 16 j = 4096 outputs ----
    #pragma unroll
    for (int k = 0; k < 16; ++k) {
        int p  = k * 256 + tid;
        int jt = p & 15;
        int it = (p >> 4) & 31;
        int o  = p >> 9;
        int i = i0 + it, j = j0 + jt;
        if (i < NO && j < NO) {
            float s = hsum[o][it][jt] + hsum[o][it + 1][jt] +
                      hsum[o][it + 2][jt] + hsum[o][it + 3][jt];
            out[((size_t)o * NO + i) * NO + j] = s;
        }
    }
}

extern "C" void kernel_launch(void* const* d_in, const int* in_sizes, int n_in,
                              void* d_out, int out_size, void* d_ws, size_t ws_size,
                              hipStream_t stream) {
    const float* x = (const float*)d_in[0];
    float* out = (float*)d_out;

    // Reference coefficient pipeline: angle = f32(f32(2o+1) * f32(pi/8));
    // coeff = correctly-rounded f32 cos/sin of that angle.
    OrientCoef cf;
    const float pi8 = (float)(M_PI / 8.0);
    for (int o = 0; o < 8; ++o) {
        float angle = (float)(2 * o + 1) * pi8;
        cf.c[o] = (float)cos((double)angle);
        cf.s[o] = (float)sin((double)angle);
    }

    dim3 grid((NO + TJ - 1) / TJ, (NO + TI - 1) / TI);   // 257 x 129
    sift_fused<<<grid, dim3(256), 0, stream>>>(x, out, cf);
}